// Round 13
// baseline (705.947 us; speedup 1.0000x reference)
//
#include <hip/hip_runtime.h>

// DecoderLayer: rms1 -> QKV -> RoPE -> causal GQA attn -> O+resid -> rms2
// -> noisy top-2 router -> sparse MoE -> resid ; aux loss.
// B=2 S=2048 D=1024 NQ=16 NKV=4 HD=64 E=8 DFF=4096 top_k=2

#define TKN 4096
#define DM  1024
#define DFF 4096
#define NE  8
#define NEG_INF -3.0e38f
#define BM 128
#define BK 64

typedef __attribute__((ext_vector_type(8))) short short8;
typedef __attribute__((ext_vector_type(4))) float f32x4;

#define MFMA16(a,b,c) __builtin_amdgcn_mfma_f32_16x16x32_bf16(a,b,c,0,0,0)

__device__ __forceinline__ short f2bf(float f){
  union{float f;unsigned u;}v; v.f=f;
  unsigned r=v.u+0x7fffu+((v.u>>16)&1u);
  return (short)(r>>16);
}
__device__ __forceinline__ float bf2f(short s){
  union{unsigned u;float f;}v; v.u=((unsigned)(unsigned short)s)<<16; return v.f;
}
__device__ __forceinline__ void gload16(const short* g, short* l){
  __builtin_amdgcn_global_load_lds(
      (const __attribute__((address_space(1))) void*)g,
      (__attribute__((address_space(3))) void*)l, 16, 0, 0);
}

// ---------------- init ----------------
__global__ void initk(int* cnt, float* imp){
  int t=threadIdx.x; if(t<8){cnt[t]=0; imp[t]=0.f;}
}

// ---------------- RMSNorm (row=block), writes bf16, optional inv_rms ----------------
template<int WI>
__global__ __launch_bounds__(256) void rms_kernel(const float* __restrict__ x,
    const float* __restrict__ w, short* __restrict__ out, float* __restrict__ invr)
{
  const int row=blockIdx.x, tid=threadIdx.x;
  const float4 xv=((const float4*)(x+(size_t)row*DM))[tid];
  float s=xv.x*xv.x+xv.y*xv.y+xv.z*xv.z+xv.w*xv.w;
  #pragma unroll
  for(int o=32;o;o>>=1) s+=__shfl_down(s,o,64);
  __shared__ float red[4];
  if((tid&63)==0) red[tid>>6]=s;
  __syncthreads();
  float r=rsqrtf((red[0]+red[1]+red[2]+red[3])*(1.f/DM)+1e-8f);
  const float4 wv=((const float4*)w)[tid];
  short* op=out+(size_t)row*DM+tid*4;
  op[0]=f2bf(wv.x*xv.x*r); op[1]=f2bf(wv.y*xv.y*r);
  op[2]=f2bf(wv.z*xv.z*r); op[3]=f2bf(wv.w*xv.w*r);
  if(WI && tid==0) invr[row]=r;
}

// ---------------- fp32 [R][C] -> bf16 [C][R] transpose (batched, vectorized) ----
__global__ __launch_bounds__(256) void transp_f2b(const float* __restrict__ in,
    short* __restrict__ out, int R, int C)
{
  __shared__ float t[64][33];
  in+=(size_t)blockIdx.z*R*C;
  out+=(size_t)blockIdx.z*R*C;
  const int r0=blockIdx.y*64, c0=blockIdx.x*32;
  const int tid=threadIdx.x;
  #pragma unroll
  for(int p=0;p<2;p++){
    int slot=p*256+tid;
    int ry=slot>>3, rx=slot&7;
    float4 v=*(const float4*)(in+(size_t)(r0+ry)*C+c0+rx*4);
    t[ry][rx*4+0]=v.x; t[ry][rx*4+1]=v.y; t[ry][rx*4+2]=v.z; t[ry][rx*4+3]=v.w;
  }
  __syncthreads();
  #pragma unroll
  for(int p=0;p<2;p++){
    int slot=p*256+tid;
    int cy=slot>>4, cx=slot&15;
    short4 o4;
    o4.x=f2bf(t[cx*4+0][cy]); o4.y=f2bf(t[cx*4+1][cy]);
    o4.z=f2bf(t[cx*4+2][cy]); o4.w=f2bf(t[cx*4+3][cy]);
    *(short4*)(out+(size_t)(c0+cy)*R+r0+cx*4)=o4;
  }
}

// ---------------- bf16 V-section transpose: QKV V part -> VT[b][kvh][64][2048] ----
__global__ __launch_bounds__(256) void transpV(const short* __restrict__ QKV,
    short* __restrict__ VT)
{
  __shared__ short t[32][33];
  const int bz=blockIdx.z, b=bz>>2, kvh=bz&3;
  const int s0=blockIdx.x*32, d0=blockIdx.y*32;
  const int tx=threadIdx.x&31, ty=threadIdx.x>>5;
  #pragma unroll
  for(int i=0;i<4;i++)
    t[ty+i*8][tx]=QKV[(size_t)(b*2048+s0+ty+i*8)*1536+1280+kvh*64+d0+tx];
  __syncthreads();
  #pragma unroll
  for(int i=0;i<4;i++)
    VT[((size_t)(b*4+kvh)*64+d0+ty+i*8)*2048+s0+tx]=t[tx][ty+i*8];
}

// ---------------- 128x128 tile GEMM, BK=64, swizzled LDS, single-buffer ----
// (r6 config: measured best — 2-barrier, 32KB LDS, conflicts=0)
template<int EPI, bool GATHER, bool MOE>
__global__ __launch_bounds__(256) void gemm128k(
    const short* __restrict__ Ab, const short* __restrict__ BTb,
    int Mfix, int N, int K, int ldb_e,
    const int* __restrict__ cnt, const int* __restrict__ off,
    const int* __restrict__ tokL,
    short* __restrict__ outb, int ldo, int ocol,
    float* __restrict__ outf, const float* __restrict__ resid,
    const float* __restrict__ biasb, int ldbias)
{
  __shared__ short As[BM*BK];
  __shared__ short Bs[BM*BK];
  const int e  = MOE ? blockIdx.z : 0;
  const int M  = MOE ? cnt[e] : Mfix;
  const int tm = blockIdx.y;
  if (tm*BM >= M) return;
  const int tn = blockIdx.x;
  const int O  = MOE ? off[e] : 0;
  const short* BT = BTb + (size_t)e * (size_t)ldb_e;

  const int tid = threadIdx.x;
  const int w = tid>>6, lane = tid&63;
  const int lr = lane&15, lg = lane>>4;
  const int wr = (w>>1)*64, wc = (w&1)*64;

  const short* pA[4]; const short* pB[4];
  #pragma unroll
  for(int i=0;i<4;i++){
    int c = i*256 + w*64 + lane;
    int cs = c ^ ((c>>3)&7);
    int r = cs>>3, k8 = (cs&7)*8;
    int grA = tm*BM + r; if (grA > M-1) grA = M-1;
    if (GATHER)      pA[i] = Ab + (size_t)tokL[O+grA]*K + k8;
    else if (MOE)    pA[i] = Ab + (size_t)(O+grA)*K + k8;
    else             pA[i] = Ab + (size_t)grA*K + k8;
    pB[i] = BT + (size_t)(tn*BM + r)*K + k8;
  }
  short* lA[4]; short* lB[4];
  #pragma unroll
  for(int i=0;i<4;i++){ lA[i]=As+i*2048+w*512; lB[i]=Bs+i*2048+w*512; }

  f32x4 acc[4][4];
  #pragma unroll
  for(int i=0;i<4;i++)
    #pragma unroll
    for(int j=0;j<4;j++) acc[i][j]=(f32x4){0.f,0.f,0.f,0.f};

  #pragma unroll
  for(int i=0;i<4;i++){ gload16(pA[i], lA[i]); gload16(pB[i], lB[i]); }

  const int koff0 = ((lg  ) ^ (lr&7))*8;
  const int koff1 = ((4+lg) ^ (lr&7))*8;

  for(int k0=0;k0<K;k0+=BK){
    __syncthreads();
    short8 af[4][2], bfr[4][2];
    #pragma unroll
    for(int mi=0;mi<4;mi++){
      const int rb=(wr+mi*16+lr)*BK;
      af[mi][0]=*(const short8*)(As+rb+koff0);
      af[mi][1]=*(const short8*)(As+rb+koff1);
    }
    #pragma unroll
    for(int ni=0;ni<4;ni++){
      const int rb=(wc+ni*16+lr)*BK;
      bfr[ni][0]=*(const short8*)(Bs+rb+koff0);
      bfr[ni][1]=*(const short8*)(Bs+rb+koff1);
    }
    __syncthreads();
    if(k0+BK<K){
      #pragma unroll
      for(int i=0;i<4;i++){ gload16(pA[i]+k0+BK, lA[i]); gload16(pB[i]+k0+BK, lB[i]); }
    }
    #pragma unroll
    for(int kk=0;kk<2;kk++)
      #pragma unroll
      for(int mi=0;mi<4;mi++)
        #pragma unroll
        for(int ni=0;ni<4;ni++)
          acc[mi][ni]=MFMA16(af[mi][kk],bfr[ni][kk],acc[mi][ni]);
  }

  #pragma unroll
  for(int mi=0;mi<4;mi++){
    const int rb = tm*BM + wr + mi*16 + 4*lg;
    #pragma unroll
    for(int ni=0;ni<4;ni++){
      const int col = tn*BM + wc + ni*16 + lr;
      f32x4 a = acc[mi][ni];
      #pragma unroll
      for(int j=0;j<4;j++){
        int r = rb + j;
        if (r < M){
          if (EPI==0){
            outb[(size_t)r*ldo + ocol + col] = f2bf(a[j]);
          } else if (EPI==1){
            size_t idx=(size_t)r*ldo + col;
            outf[idx] = resid[idx] + a[j];
          } else if (EPI==2){
            float v=a[j]+biasb[(size_t)e*ldbias+col];
            v=v/(1.f+__expf(-v));
            outb[(size_t)(O+r)*ldo + col]=f2bf(v);
          } else {
            outb[(size_t)(O+r)*ldo + col]=f2bf(a[j]+biasb[(size_t)e*ldbias+col]);
          }
        }
      }
    }
  }
}

// ---------------- RoPE in-place on bf16 QKV (combined [4096][1536]) ----------
__global__ __launch_bounds__(256) void rope_kernel(short* __restrict__ QKV)
{
  int t=blockIdx.x*256+threadIdx.x;
  if(t>=2621440) return;
  size_t addr; int s,i;
  if(t<2097152){                  // Q
    i=t&31; int rh=t>>5; int bs=rh>>4, h=rh&15; s=bs&2047;
    addr=(size_t)bs*1536+h*64+2*i;
  }else{                          // K
    t-=2097152;
    i=t&31; int rh=t>>5; int bs=rh>>2, h=rh&3; s=bs&2047;
    addr=(size_t)bs*1536+1024+h*64+2*i;
  }
  float inv=__expf(-(float)i*0.28782313662425572f); // ln(10000)/32
  float ang=(float)s*inv;
  float c=__cosf(ang), sn=__sinf(ang);
  float xe=bf2f(QKV[addr]), xo=bf2f(QKV[addr+1]);
  QKV[addr]  =f2bf(xe*c-xo*sn);
  QKV[addr+1]=f2bf(xo*c+xe*sn);
}

// ---------------- causal GQA flash attention v4: KVBLK=128 ----------------
// grid (16, NQ, B); qt balanced across b. 4 waves; wave owns 32 q rows.
// K tile [128 kv][64 d], V^T tile [64 d][128 kv], both gload_lds-staged with
// row&7 chunk swizzle. Schedule per tile: barrier -> QK^T (kf in halves) ->
// vf[4][4] to regs -> barrier -> stage(next) [flies under softmax+PV] ->
// softmax -> Ps -> PV. Q pre-scaled by 0.125 (exact).
__global__ __launch_bounds__(256) void attn_kernel(
    const short* __restrict__ QKV, const short* __restrict__ VT,
    short* __restrict__ O)
{
  const int b=blockIdx.z;
  const int qt = b==0 ? (int)blockIdx.x : 15-(int)blockIdx.x;
  const int h=blockIdx.y;
  const int kvh=h>>2;
  const int tid=threadIdx.x;
  const int w=tid>>6, lane=tid&63;
  const int lr=lane&15, lg=lane>>4;
  const int q0w=qt*128+w*32;

  __shared__ short Ks[128*64];     // [kv][d]
  __shared__ short Vs[64*128];     // [d][kv]
  __shared__ short Ps[4][32][136];

  // Q fragments pre-scaled by 1/8 (power of 2: bf16-exact)
  short8 qf[2][2];
  #pragma unroll
  for(int qb=0;qb<2;qb++)
    #pragma unroll
    for(int ks=0;ks<2;ks++){
      short8 q0=*(const short8*)(QKV+(size_t)(b*2048+q0w+qb*16+lr)*1536+h*64+ks*32+lg*8);
      #pragma unroll
      for(int z=0;z<8;z++) q0[z]=f2bf(bf2f(q0[z])*0.125f);
      qf[qb][ks]=q0;
    }

  f32x4 o[2][4];
  float mj[2][4], lj[2][4];
  #pragma unroll
  for(int qb=0;qb<2;qb++)
    #pragma unroll
    for(int j=0;j<4;j++){
      mj[qb][j]=NEG_INF; lj[qb][j]=0.f;
      #pragma unroll
      for(int db=0;db<4;db++) o[qb][db]=(f32x4){0.f,0.f,0.f,0.f};
    }

  // staging pointers: chunk c = i*256 + w*64 + lane
  const short* gK[4]; const short* gV[4];
  #pragma unroll
  for(int i=0;i<4;i++){
    int c=i*256+w*64+lane;
    int rK=c>>3, pK=((c&7)^(rK&7))*8;           // K: 8 chunks/row of 64d
    gK[i]=QKV + (size_t)(b*2048+rK)*1536 + 1024 + kvh*64 + pK;
    int rV=c>>4, pV=((c&15)^(rV&7))*8;          // V: 16 chunks/row of 128kv
    gV[i]=VT + ((size_t)(b*4+kvh)*64+rV)*2048 + pV;
  }
  auto stage=[&](int kv0){
    #pragma unroll
    for(int i=0;i<4;i++){
      gload16(gK[i]+(size_t)kv0*1536, Ks+(i*256+w*64)*8);
      gload16(gV[i]+kv0,              Vs+(i*256+w*64)*8);
    }
  };

  const int ntile=qt+1;
  stage(0);
  for(int it=0;it<ntile;it++){
    const int kv0=it*128;
    __syncthreads();                       // tile ready
    // QK^T (kf in halves), s[qb][nb] over 8 nb-blocks of 16 kv
    f32x4 s[2][8];
    #pragma unroll
    for(int kh=0;kh<2;kh++){
      short8 kf[4][2];
      #pragma unroll
      for(int n4=0;n4<4;n4++){
        const int row=(kh*4+n4)*16+lr;
        #pragma unroll
        for(int ks=0;ks<2;ks++)
          kf[n4][ks]=*(const short8*)(Ks+row*64+(((ks*4+lg)^(row&7))*8));
      }
      #pragma unroll
      for(int qb=0;qb<2;qb++)
        #pragma unroll
        for(int n4=0;n4<4;n4++){
          f32x4 t=(f32x4){0.f,0.f,0.f,0.f};
          t=MFMA16(qf[qb][0],kf[n4][0],t);
          t=MFMA16(qf[qb][1],kf[n4][1],t);
          s[qb][kh*4+n4]=t;
        }
    }
    // all V fragments to regs (frees LDS for next stage)
    short8 vf[4][4];
    #pragma unroll
    for(int db=0;db<4;db++){
      const int row=db*16+lr;
      #pragma unroll
      for(int ks=0;ks<4;ks++)
        vf[db][ks]=*(const short8*)(Vs+row*128+(((ks*4+lg)^(row&7))*8));
    }
    __syncthreads();                       // all K/V reads done
    if(it+1<ntile) stage(kv0+128);         // flies under softmax+PV

    // mask + row max
    const bool edge=(it==qt);
    float tmx[2][4];
    #pragma unroll
    for(int qb=0;qb<2;qb++)
      #pragma unroll
      for(int j=0;j<4;j++){
        float mx=NEG_INF;
        #pragma unroll
        for(int nb=0;nb<8;nb++){
          float v=s[qb][nb][j];
          if(edge){
            if(kv0+nb*16+lr > q0w+qb*16+4*lg+j) v=NEG_INF;
          }
          s[qb][nb][j]=v;
          mx=fmaxf(mx,v);
        }
        tmx[qb][j]=mx;
      }
    #pragma unroll
    for(int qb=0;qb<2;qb++)
      #pragma unroll
      for(int j=0;j<4;j++){
        #pragma unroll
        for(int od=1;od<16;od<<=1) tmx[qb][j]=fmaxf(tmx[qb][j],__shfl_xor(tmx[qb][j],od,64));
      }
    // online softmax update
    #pragma unroll
    for(int qb=0;qb<2;qb++)
      #pragma unroll
      for(int j=0;j<4;j++){
        float mn=fmaxf(mj[qb][j],tmx[qb][j]);
        float al=__expf(mj[qb][j]-mn);
        mj[qb][j]=mn;
        float rs=0.f;
        #pragma unroll
        for(int nb=0;nb<8;nb++){
          float pv=__expf(s[qb][nb][j]-mn);
          s[qb][nb][j]=pv;
          rs+=pv;
        }
        #pragma unroll
        for(int od=1;od<16;od<<=1) rs+=__shfl_xor(rs,od,64);
        lj[qb][j]=lj[qb][j]*al+rs;
        #pragma unroll
        for(int db=0;db<4;db++) o[qb][db][j]*=al;
      }
    // P -> LDS (bf16), then A-fragments
    #pragma unroll
    for(int qb=0;qb<2;qb++)
      #pragma unroll
      for(int nb=0;nb<8;nb++)
        #pragma unroll
        for(int j=0;j<4;j++)
          Ps[w][qb*16+4*lg+j][nb*16+lr]=f2bf(s[qb][nb][j]);
    short8 pa[2][4];
    #pragma unroll
    for(int qb=0;qb<2;qb++)
      #pragma unroll
      for(int ks=0;ks<4;ks++)
        pa[qb][ks]=*(const short8*)(&Ps[w][qb*16+lr][ks*32+lg*8]);
    // PV from registers
    #pragma unroll
    for(int qb=0;qb<2;qb++)
      #pragma unroll
      for(int ks=0;ks<4;ks++)
        #pragma unroll
        for(int db=0;db<4;db++)
          o[qb][db]=MFMA16(pa[qb][ks],vf[db][ks],o[qb][db]);
  }

  #pragma unroll
  for(int qb=0;qb<2;qb++)
    #pragma unroll
    for(int j=0;j<4;j++){
      const int qpos=q0w+qb*16+4*lg+j;
      const float inv=1.f/lj[qb][j];
      size_t base=(size_t)(b*2048+qpos)*DM+h*64;
      #pragma unroll
      for(int db=0;db<4;db++)
        O[base+db*16+lr]=f2bf(o[qb][db][j]*inv);
    }
}

// ---------------- router ----------------
__global__ __launch_bounds__(256) void router_kernel(
    const float* __restrict__ xmid, const float* __restrict__ n2w,
    const float* __restrict__ invr,
    const float* __restrict__ gate_w, const float* __restrict__ gate_b,
    const float* __restrict__ noise_w, const float* __restrict__ noise_b,
    const float* __restrict__ rnoise,
    int* __restrict__ tokE, float* __restrict__ tokS,
    int* __restrict__ cnt, float* __restrict__ imp)
{
  const int t=blockIdx.x, tid=threadIdx.x;
  const float r=invr[t];
  float acc[16];
  #pragma unroll
  for(int e=0;e<16;e++) acc[e]=0.f;
  const float* xr=xmid+(size_t)t*DM;
  #pragma unroll
  for(int i=0;i<4;i++){
    int d=tid*4+i;
    float h=n2w[d]*xr[d]*r;
    const float* gwr=gate_w+(size_t)d*8;
    const float* nwr=noise_w+(size_t)d*8;
    #pragma unroll
    for(int e=0;e<8;e++){ acc[e]+=h*gwr[e]; acc[8+e]+=h*nwr[e]; }
  }
  #pragma unroll
  for(int e=0;e<16;e++){
    #pragma unroll
    for(int o=32;o;o>>=1) acc[e]+=__shfl_down(acc[e],o,64);
  }
  __shared__ float red[4][16];
  if((tid&63)==0){
    #pragma unroll
    for(int e=0;e<16;e++) red[tid>>6][e]=acc[e];
  }
  __syncthreads();
  if(tid==0){
    float lgt[8];
    #pragma unroll
    for(int e=0;e<8;e++){
      float g =red[0][e]+red[1][e]+red[2][e]+red[3][e];
      float nz=red[0][8+e]+red[1][8+e]+red[2][8+e]+red[3][8+e];
      lgt[e]=g+gate_b[e]+nz+noise_b[e]+rnoise[(size_t)t*8+e];
    }
    int i1=0;
    for(int e=1;e<8;e++) if(lgt[e]>lgt[i1]) i1=e;
    int i2=(i1==0)?1:0;
    for(int e=0;e<8;e++) if(e!=i1 && lgt[e]>lgt[i2]) i2=e;
    float e2=expf(lgt[i2]-lgt[i1]);
    float den=1.f+e2;
    float s1=1.f/den, s2=e2/den;
    tokE[2*t]=i1; tokE[2*t+1]=i2;
    tokS[2*t]=s1; tokS[2*t+1]=s2;
    atomicAdd(&cnt[i1],1); atomicAdd(&cnt[i2],1);
    atomicAdd(&imp[i1],s1); atomicAdd(&imp[i2],s2);
  }
}

// ---------------- offsets scan + aux loss ----------------
__global__ void scan_aux(const int* cnt, int* off, int* cur, const float* imp, float* auxout)
{
  if(threadIdx.x==0){
    int o=0;
    for(int e=0;e<8;e++){ off[e]=o; o+=cnt[e]; cur[e]=0; }
    float u=0.125f, s=0.f;
    for(int e=0;e<8;e++) s+=u*(logf(u)-logf(imp[e]*(1.f/4096.f)+1e-8f));
    auxout[0]=s;
  }
}

// ---------------- compact token lists per expert ----------------
__global__ __launch_bounds__(256) void scatter_kernel(const int* __restrict__ tokE,
    const int* __restrict__ off, int* __restrict__ cur,
    int* __restrict__ tokL, int* __restrict__ slotOf)
{
  int t=blockIdx.x*256+threadIdx.x;
  if(t>=TKN) return;
  #pragma unroll
  for(int j=0;j<2;j++){
    int e=tokE[2*t+j];
    int idx=atomicAdd(&cur[e],1);
    int slot=off[e]+idx;
    tokL[slot]=t;
    slotOf[2*t+j]=slot;
  }
}

// ---------------- combine: dout[t] += s1*eo[slot1] + s2*eo[slot2] (eo bf16) ----
__global__ __launch_bounds__(256) void combine_kernel(const short* __restrict__ eo,
    const int* __restrict__ slotOf, const float* __restrict__ tokS,
    float* __restrict__ dout)
{
  const int t=blockIdx.x, d=threadIdx.x*4;
  const int s1=slotOf[2*t], s2=slotOf[2*t+1];
  const float w1=tokS[2*t], w2=tokS[2*t+1];
  float4 o=*(float4*)(dout+(size_t)t*DM+d);
  const short4 e1=*(const short4*)(eo+(size_t)s1*DM+d);
  const short4 e2=*(const short4*)(eo+(size_t)s2*DM+d);
  o.x+=w1*bf2f(e1.x)+w2*bf2f(e2.x);
  o.y+=w1*bf2f(e1.y)+w2*bf2f(e2.y);
  o.z+=w1*bf2f(e1.z)+w2*bf2f(e2.z);
  o.w+=w1*bf2f(e1.w)+w2*bf2f(e2.w);
  *(float4*)(dout+(size_t)t*DM+d)=o;
}

extern "C" void kernel_launch(void* const* d_in, const int* in_sizes, int n_in,
                              void* d_out, int out_size, void* d_ws, size_t ws_size,
                              hipStream_t stream)
{
  const float* x   =(const float*)d_in[0];
  const float* rn  =(const float*)d_in[1];
  const float* n1w =(const float*)d_in[2];
  const float* n2w =(const float*)d_in[3];
  const float* wq  =(const float*)d_in[4];
  const float* wk  =(const float*)d_in[5];
  const float* wv  =(const float*)d_in[6];
  const float* wo  =(const float*)d_in[7];
  const float* gw  =(const float*)d_in[8];
  const float* gb  =(const float*)d_in[9];
  const float* nw  =(const float*)d_in[10];
  const float* nb  =(const float*)d_in[11];
  const float* ew1 =(const float*)d_in[12];
  const float* eb1 =(const float*)d_in[13];
  const float* ew2 =(const float*)d_in[14];
  const float* eb2 =(const float*)d_in[15];
  float* dout=(float*)d_out;

  char* p=(char*)d_ws;
  auto take=[&](size_t n){ char* q=p; p+=(n+255)&~(size_t)255; return q; };
  short* h1    =(short*)take((size_t)TKN*DM*2);
  short* wqkvT =(short*)take((size_t)1536*DM*2);
  short* woT   =(short*)take((size_t)DM*DM*2);
  short* ew1T  =(short*)take((size_t)NE*DFF*DM*2);
  short* ew2T  =(short*)take((size_t)NE*DM*DFF*2);
  short* QKV   =(short*)take((size_t)TKN*1536*2);
  short* VTb   =(short*)take((size_t)8*64*2048*2);
  short* Ob    =(short*)take((size_t)TKN*DM*2);
  float* invr  =(float*)take((size_t)TKN*4);
  short* hh    =(short*)take((size_t)2*TKN*DFF*2);
  short* eoB   =(short*)take((size_t)2*TKN*DM*2);
  int*   tokE  =(int*)take((size_t)TKN*2*4);
  float* tokS  =(float*)take((size_t)TKN*2*4);
  int*   tokL  =(int*)take((size_t)2*TKN*4);
  int*   slotOf=(int*)take((size_t)TKN*2*4);
  int*   cnt   =(int*)take(256);
  int*   off   =cnt+8;
  int*   cur   =cnt+16;
  float* imp   =(float*)(cnt+24);

  initk<<<1,64,0,stream>>>(cnt,imp);
  rms_kernel<0><<<TKN,256,0,stream>>>(x,n1w,h1,nullptr);
  transp_f2b<<<dim3(32,16,1),256,0,stream>>>(wq,wqkvT,DM,DM);
  transp_f2b<<<dim3(8,16,1),256,0,stream>>>(wk,wqkvT+(size_t)1024*DM,DM,256);
  transp_f2b<<<dim3(8,16,1),256,0,stream>>>(wv,wqkvT+(size_t)1280*DM,DM,256);
  transp_f2b<<<dim3(32,16,1),256,0,stream>>>(wo,woT,DM,DM);
  transp_f2b<<<dim3(128,16,8),256,0,stream>>>(ew1,ew1T,DM,DFF);
  transp_f2b<<<dim3(32,64,8),256,0,stream>>>(ew2,ew2T,DFF,DM);

  // QKV projection: [4096][1536]
  gemm128k<0,false,false><<<dim3(12,32),256,0,stream>>>(
      h1,wqkvT,TKN,1536,DM,0, nullptr,nullptr,nullptr,
      QKV,1536,0, nullptr,nullptr, nullptr,0);
  transpV<<<dim3(64,2,8),256,0,stream>>>(QKV,VTb);
  rope_kernel<<<10240,256,0,stream>>>(QKV);
  attn_kernel<<<dim3(16,16,2),256,0,stream>>>(QKV,VTb,Ob);
  // O projection + residual
  gemm128k<1,false,false><<<dim3(8,32),256,0,stream>>>(
      Ob,woT,TKN,DM,DM,0, nullptr,nullptr,nullptr,
      nullptr,DM,0, dout,x, nullptr,0);

  rms_kernel<1><<<TKN,256,0,stream>>>(dout,n2w,h1,invr);
  router_kernel<<<TKN,256,0,stream>>>(dout,n2w,invr,gw,gb,nw,nb,rn,tokE,tokS,cnt,imp);
  scan_aux<<<1,64,0,stream>>>(cnt,off,cur,imp,dout+(size_t)TKN*DM);
  scatter_kernel<<<16,256,0,stream>>>(tokE,off,cur,tokL,slotOf);

  // MoE GEMM1: hh = silu(h2[tokL] @ ew1 + eb1)
  gemm128k<2,true,true><<<dim3(32,32,8),256,0,stream>>>(
      h1,ew1T,0,DFF,DM,DFF*DM, cnt,off,tokL,
      hh,DFF,0, nullptr,nullptr, eb1,DFF);
  // MoE GEMM2: eo = hh @ ew2 + eb2   (bf16 output)
  gemm128k<3,false,true><<<dim3(8,32,8),256,0,stream>>>(
      hh,ew2T,0,DM,DFF,DM*DFF, cnt,off,nullptr,
      eoB,DM,0, nullptr,nullptr, eb2,DM);
  combine_kernel<<<TKN,256,0,stream>>>(eoB,slotOf,tokS,dout);
  (void)in_sizes;(void)n_in;(void)out_size;(void)ws_size;
}

// Round 16
// 698.864 us; speedup vs baseline: 1.0101x; 1.0101x over previous
//
#include <hip/hip_runtime.h>

// DecoderLayer: rms1 -> QKV -> RoPE -> causal GQA attn -> O+resid -> rms2
// -> noisy top-2 router -> sparse MoE -> resid ; aux loss.
// B=2 S=2048 D=1024 NQ=16 NKV=4 HD=64 E=8 DFF=4096 top_k=2
// Best measured build (round 12): 697.7 us.

#define TKN 4096
#define DM  1024
#define DFF 4096
#define NE  8
#define NEG_INF -3.0e38f
#define BM 128
#define BK 64

typedef __attribute__((ext_vector_type(8))) short short8;
typedef __attribute__((ext_vector_type(4))) float f32x4;

#define MFMA16(a,b,c) __builtin_amdgcn_mfma_f32_16x16x32_bf16(a,b,c,0,0,0)

__device__ __forceinline__ short f2bf(float f){
  union{float f;unsigned u;}v; v.f=f;
  unsigned r=v.u+0x7fffu+((v.u>>16)&1u);
  return (short)(r>>16);
}
__device__ __forceinline__ float bf2f(short s){
  union{unsigned u;float f;}v; v.u=((unsigned)(unsigned short)s)<<16; return v.f;
}
__device__ __forceinline__ void gload16(const short* g, short* l){
  __builtin_amdgcn_global_load_lds(
      (const __attribute__((address_space(1))) void*)g,
      (__attribute__((address_space(3))) void*)l, 16, 0, 0);
}

// ---------------- init ----------------
__global__ void initk(int* cnt, float* imp){
  int t=threadIdx.x; if(t<8){cnt[t]=0; imp[t]=0.f;}
}

// ---------------- RMSNorm (row=block), writes bf16, optional inv_rms ----------------
template<int WI>
__global__ __launch_bounds__(256) void rms_kernel(const float* __restrict__ x,
    const float* __restrict__ w, short* __restrict__ out, float* __restrict__ invr)
{
  const int row=blockIdx.x, tid=threadIdx.x;
  const float4 xv=((const float4*)(x+(size_t)row*DM))[tid];
  float s=xv.x*xv.x+xv.y*xv.y+xv.z*xv.z+xv.w*xv.w;
  #pragma unroll
  for(int o=32;o;o>>=1) s+=__shfl_down(s,o,64);
  __shared__ float red[4];
  if((tid&63)==0) red[tid>>6]=s;
  __syncthreads();
  float r=rsqrtf((red[0]+red[1]+red[2]+red[3])*(1.f/DM)+1e-8f);
  const float4 wv=((const float4*)w)[tid];
  short* op=out+(size_t)row*DM+tid*4;
  op[0]=f2bf(wv.x*xv.x*r); op[1]=f2bf(wv.y*xv.y*r);
  op[2]=f2bf(wv.z*xv.z*r); op[3]=f2bf(wv.w*xv.w*r);
  if(WI && tid==0) invr[row]=r;
}

// ---------------- fp32 [R][C] -> bf16 [C][R] transpose (batched, vectorized) ----
__global__ __launch_bounds__(256) void transp_f2b(const float* __restrict__ in,
    short* __restrict__ out, int R, int C)
{
  __shared__ float t[64][33];
  in+=(size_t)blockIdx.z*R*C;
  out+=(size_t)blockIdx.z*R*C;
  const int r0=blockIdx.y*64, c0=blockIdx.x*32;
  const int tid=threadIdx.x;
  #pragma unroll
  for(int p=0;p<2;p++){
    int slot=p*256+tid;
    int ry=slot>>3, rx=slot&7;
    float4 v=*(const float4*)(in+(size_t)(r0+ry)*C+c0+rx*4);
    t[ry][rx*4+0]=v.x; t[ry][rx*4+1]=v.y; t[ry][rx*4+2]=v.z; t[ry][rx*4+3]=v.w;
  }
  __syncthreads();
  #pragma unroll
  for(int p=0;p<2;p++){
    int slot=p*256+tid;
    int cy=slot>>4, cx=slot&15;
    short4 o4;
    o4.x=f2bf(t[cx*4+0][cy]); o4.y=f2bf(t[cx*4+1][cy]);
    o4.z=f2bf(t[cx*4+2][cy]); o4.w=f2bf(t[cx*4+3][cy]);
    *(short4*)(out+(size_t)(c0+cy)*R+r0+cx*4)=o4;
  }
}

// ---------------- bf16 V-section transpose: QKV V part -> VT[b][kvh][64][2048] ----
__global__ __launch_bounds__(256) void transpV(const short* __restrict__ QKV,
    short* __restrict__ VT)
{
  __shared__ short t[32][33];
  const int bz=blockIdx.z, b=bz>>2, kvh=bz&3;
  const int s0=blockIdx.x*32, d0=blockIdx.y*32;
  const int tx=threadIdx.x&31, ty=threadIdx.x>>5;
  #pragma unroll
  for(int i=0;i<4;i++)
    t[ty+i*8][tx]=QKV[(size_t)(b*2048+s0+ty+i*8)*1536+1280+kvh*64+d0+tx];
  __syncthreads();
  #pragma unroll
  for(int i=0;i<4;i++)
    VT[((size_t)(b*4+kvh)*64+d0+ty+i*8)*2048+s0+tx]=t[tx][ty+i*8];
}

// ---------------- 128x128 tile GEMM, BK=64, swizzled LDS, single-buffer ----
// (r6 config: measured best — 2-barrier, 32KB LDS, conflicts=0)
// LDS chunk (row,col8) holds logical k-chunk col8 ^ (row&7)  (both tiles)
// EPI 0: bf16 store (ldo,ocol)        EPI 1: outf = resid + acc (fp32)
// EPI 2: silu(acc+bias) bf16, MoE row O+r   EPI 3: (acc+bias) bf16, MoE row O+r
template<int EPI, bool GATHER, bool MOE>
__global__ __launch_bounds__(256) void gemm128k(
    const short* __restrict__ Ab, const short* __restrict__ BTb,
    int Mfix, int N, int K, int ldb_e,
    const int* __restrict__ cnt, const int* __restrict__ off,
    const int* __restrict__ tokL,
    short* __restrict__ outb, int ldo, int ocol,
    float* __restrict__ outf, const float* __restrict__ resid,
    const float* __restrict__ biasb, int ldbias)
{
  __shared__ short As[BM*BK];
  __shared__ short Bs[BM*BK];
  const int e  = MOE ? blockIdx.z : 0;
  const int M  = MOE ? cnt[e] : Mfix;
  const int tm = blockIdx.y;
  if (tm*BM >= M) return;
  const int tn = blockIdx.x;
  const int O  = MOE ? off[e] : 0;
  const short* BT = BTb + (size_t)e * (size_t)ldb_e;

  const int tid = threadIdx.x;
  const int w = tid>>6, lane = tid&63;
  const int lr = lane&15, lg = lane>>4;
  const int wr = (w>>1)*64, wc = (w&1)*64;

  const short* pA[4]; const short* pB[4];
  #pragma unroll
  for(int i=0;i<4;i++){
    int c = i*256 + w*64 + lane;
    int cs = c ^ ((c>>3)&7);
    int r = cs>>3, k8 = (cs&7)*8;
    int grA = tm*BM + r; if (grA > M-1) grA = M-1;
    if (GATHER)      pA[i] = Ab + (size_t)tokL[O+grA]*K + k8;
    else if (MOE)    pA[i] = Ab + (size_t)(O+grA)*K + k8;
    else             pA[i] = Ab + (size_t)grA*K + k8;
    pB[i] = BT + (size_t)(tn*BM + r)*K + k8;
  }
  short* lA[4]; short* lB[4];
  #pragma unroll
  for(int i=0;i<4;i++){ lA[i]=As+i*2048+w*512; lB[i]=Bs+i*2048+w*512; }

  f32x4 acc[4][4];
  #pragma unroll
  for(int i=0;i<4;i++)
    #pragma unroll
    for(int j=0;j<4;j++) acc[i][j]=(f32x4){0.f,0.f,0.f,0.f};

  #pragma unroll
  for(int i=0;i<4;i++){ gload16(pA[i], lA[i]); gload16(pB[i], lB[i]); }

  const int koff0 = ((lg  ) ^ (lr&7))*8;
  const int koff1 = ((4+lg) ^ (lr&7))*8;

  for(int k0=0;k0<K;k0+=BK){
    __syncthreads();
    short8 af[4][2], bfr[4][2];
    #pragma unroll
    for(int mi=0;mi<4;mi++){
      const int rb=(wr+mi*16+lr)*BK;
      af[mi][0]=*(const short8*)(As+rb+koff0);
      af[mi][1]=*(const short8*)(As+rb+koff1);
    }
    #pragma unroll
    for(int ni=0;ni<4;ni++){
      const int rb=(wc+ni*16+lr)*BK;
      bfr[ni][0]=*(const short8*)(Bs+rb+koff0);
      bfr[ni][1]=*(const short8*)(Bs+rb+koff1);
    }
    __syncthreads();
    if(k0+BK<K){
      #pragma unroll
      for(int i=0;i<4;i++){ gload16(pA[i]+k0+BK, lA[i]); gload16(pB[i]+k0+BK, lB[i]); }
    }
    #pragma unroll
    for(int kk=0;kk<2;kk++)
      #pragma unroll
      for(int mi=0;mi<4;mi++)
        #pragma unroll
        for(int ni=0;ni<4;ni++)
          acc[mi][ni]=MFMA16(af[mi][kk],bfr[ni][kk],acc[mi][ni]);
  }

  #pragma unroll
  for(int mi=0;mi<4;mi++){
    const int rb = tm*BM + wr + mi*16 + 4*lg;
    #pragma unroll
    for(int ni=0;ni<4;ni++){
      const int col = tn*BM + wc + ni*16 + lr;
      f32x4 a = acc[mi][ni];
      #pragma unroll
      for(int j=0;j<4;j++){
        int r = rb + j;
        if (r < M){
          if (EPI==0){
            outb[(size_t)r*ldo + ocol + col] = f2bf(a[j]);
          } else if (EPI==1){
            size_t idx=(size_t)r*ldo + col;
            outf[idx] = resid[idx] + a[j];
          } else if (EPI==2){
            float v=a[j]+biasb[(size_t)e*ldbias+col];
            v=v/(1.f+__expf(-v));
            outb[(size_t)(O+r)*ldo + col]=f2bf(v);
          } else {
            outb[(size_t)(O+r)*ldo + col]=f2bf(a[j]+biasb[(size_t)e*ldbias+col]);
          }
        }
      }
    }
  }
}

// ---------------- RoPE in-place on bf16 QKV (combined [4096][1536]) ----------
__global__ __launch_bounds__(256) void rope_kernel(short* __restrict__ QKV)
{
  int t=blockIdx.x*256+threadIdx.x;
  if(t>=2621440) return;
  size_t addr; int s,i;
  if(t<2097152){                  // Q
    i=t&31; int rh=t>>5; int bs=rh>>4, h=rh&15; s=bs&2047;
    addr=(size_t)bs*1536+h*64+2*i;
  }else{                          // K
    t-=2097152;
    i=t&31; int rh=t>>5; int bs=rh>>2, h=rh&3; s=bs&2047;
    addr=(size_t)bs*1536+1024+h*64+2*i;
  }
  float inv=__expf(-(float)i*0.28782313662425572f); // ln(10000)/32
  float ang=(float)s*inv;
  float c=__cosf(ang), sn=__sinf(ang);
  float xe=bf2f(QKV[addr]), xo=bf2f(QKV[addr+1]);
  QKV[addr]  =f2bf(xe*c-xo*sn);
  QKV[addr+1]=f2bf(xo*c+xe*sn);
}

// ---------------- causal GQA flash attention v3 (load-balanced) ----------------
// grid (16, NQ, B); qt = (b==0) ? x : 15-x  -> co-resident block pairs carry
// complementary causal workloads. 4 waves; wave owns 32 q rows; KVBLK=64.
// K tile [64 kv][64 d] and VT tile [64 d][64 kv] staged via global_load_lds,
// both-sides XOR swizzle (8-elem chunks XOR'd by row&7).
__global__ __launch_bounds__(256) void attn_kernel(
    const short* __restrict__ QKV, const short* __restrict__ VT,
    short* __restrict__ O)
{
  const int b=blockIdx.z;
  const int qt = b==0 ? (int)blockIdx.x : 15-(int)blockIdx.x;
  const int h=blockIdx.y;
  const int kvh=h>>2;
  const int tid=threadIdx.x;
  const int w=tid>>6, lane=tid&63;
  const int lr=lane&15, lg=lane>>4;
  const int q0w=qt*128+w*32;

  __shared__ short Ks[64*64];
  __shared__ short Vs[64*64];
  __shared__ short Ps[4][32][72];

  short8 qf[2][2];
  #pragma unroll
  for(int qb=0;qb<2;qb++)
    #pragma unroll
    for(int ks=0;ks<2;ks++)
      qf[qb][ks]=*(const short8*)(QKV+(size_t)(b*2048+q0w+qb*16+lr)*1536+h*64+ks*32+lg*8);

  f32x4 o[2][4];
  float mj[2][4], lj[2][4];
  #pragma unroll
  for(int qb=0;qb<2;qb++)
    #pragma unroll
    for(int j=0;j<4;j++){
      mj[qb][j]=NEG_INF; lj[qb][j]=0.f;
      #pragma unroll
      for(int db=0;db<4;db++) o[qb][db]=(f32x4){0.f,0.f,0.f,0.f};
    }

  const int c1=w*64+lane;
  const int r1=c1>>3, swz=((c1&7)^(r1&7))*8;
  const short* gKb = QKV + 1024 + kvh*64 + (size_t)r1*1536 + swz;
  const short* gVb = VT + ((size_t)(b*4+kvh)*64 + r1)*2048 + swz;
  short* lK1=Ks+w*512; short* lK2=Ks+2048+w*512;
  short* lV1=Vs+w*512; short* lV2=Vs+2048+w*512;

  auto stage=[&](int kv0){
    const short* gK = gKb + (size_t)(b*2048+kv0)*1536;
    gload16(gK, lK1);
    gload16(gK + (size_t)32*1536, lK2);
    const short* gV = gVb + kv0;
    gload16(gV, lV1);
    gload16(gV + (size_t)32*2048, lV2);
  };

  const int kvend=qt*128+127;
  stage(0);
  for(int kv0=0;kv0<=kvend;kv0+=64){
    __syncthreads();
    const bool act = (kv0 <= q0w+31);
    short8 kf[4][2], vf[4][2];
    if(act){
      #pragma unroll
      for(int nb=0;nb<4;nb++)
        #pragma unroll
        for(int ks=0;ks<2;ks++)
          kf[nb][ks]=*(const short8*)(Ks+(nb*16+lr)*64+(((ks*4+lg)^(lr&7))*8));
      #pragma unroll
      for(int db=0;db<4;db++)
        #pragma unroll
        for(int ks=0;ks<2;ks++)
          vf[db][ks]=*(const short8*)(Vs+(db*16+lr)*64+(((ks*4+lg)^(lr&7))*8));
    }
    __syncthreads();
    if(kv0+64<=kvend) stage(kv0+64);
    if(!act) continue;

    f32x4 s[2][4];
    #pragma unroll
    for(int qb=0;qb<2;qb++)
      #pragma unroll
      for(int nb=0;nb<4;nb++){
        f32x4 t=(f32x4){0.f,0.f,0.f,0.f};
        t=MFMA16(qf[qb][0],kf[nb][0],t);
        t=MFMA16(qf[qb][1],kf[nb][1],t);
        s[qb][nb]=t;
      }

    const bool edge = (kv0+63 > q0w);
    float tmx[2][4];
    #pragma unroll
    for(int qb=0;qb<2;qb++)
      #pragma unroll
      for(int j=0;j<4;j++){
        float mx=NEG_INF;
        #pragma unroll
        for(int nb=0;nb<4;nb++){
          float v=s[qb][nb][j]*0.125f;
          if(edge){
            if(kv0+nb*16+lr > q0w+qb*16+4*lg+j) v=NEG_INF;
          }
          s[qb][nb][j]=v;
          mx=fmaxf(mx,v);
        }
        tmx[qb][j]=mx;
      }
    #pragma unroll
    for(int qb=0;qb<2;qb++)
      #pragma unroll
      for(int j=0;j<4;j++){
        #pragma unroll
        for(int od=1;od<16;od<<=1) tmx[qb][j]=fmaxf(tmx[qb][j],__shfl_xor(tmx[qb][j],od,64));
      }
    #pragma unroll
    for(int qb=0;qb<2;qb++)
      #pragma unroll
      for(int j=0;j<4;j++){
        float mn=fmaxf(mj[qb][j],tmx[qb][j]);
        float al=__expf(mj[qb][j]-mn);
        mj[qb][j]=mn;
        float rs=0.f;
        #pragma unroll
        for(int nb=0;nb<4;nb++){
          float pv=__expf(s[qb][nb][j]-mn);
          s[qb][nb][j]=pv;
          rs+=pv;
        }
        #pragma unroll
        for(int od=1;od<16;od<<=1) rs+=__shfl_xor(rs,od,64);
        lj[qb][j]=lj[qb][j]*al+rs;
        #pragma unroll
        for(int db=0;db<4;db++) o[qb][db][j]*=al;
      }
    #pragma unroll
    for(int qb=0;qb<2;qb++)
      #pragma unroll
      for(int nb=0;nb<4;nb++)
        #pragma unroll
        for(int j=0;j<4;j++)
          Ps[w][qb*16+4*lg+j][nb*16+lr]=f2bf(s[qb][nb][j]);
    short8 pa[2][2];
    #pragma unroll
    for(int qb=0;qb<2;qb++)
      #pragma unroll
      for(int ks=0;ks<2;ks++)
        pa[qb][ks]=*(const short8*)(&Ps[w][qb*16+lr][ks*32+lg*8]);
    #pragma unroll
    for(int qb=0;qb<2;qb++)
      #pragma unroll
      for(int db=0;db<4;db++){
        o[qb][db]=MFMA16(pa[qb][0],vf[db][0],o[qb][db]);
        o[qb][db]=MFMA16(pa[qb][1],vf[db][1],o[qb][db]);
      }
  }

  #pragma unroll
  for(int qb=0;qb<2;qb++)
    #pragma unroll
    for(int j=0;j<4;j++){
      const int qpos=q0w+qb*16+4*lg+j;
      const float inv=1.f/lj[qb][j];
      size_t base=(size_t)(b*2048+qpos)*DM+h*64;
      #pragma unroll
      for(int db=0;db<4;db++)
        O[base+db*16+lr]=f2bf(o[qb][db][j]*inv);
    }
}

// ---------------- router ----------------
__global__ __launch_bounds__(256) void router_kernel(
    const float* __restrict__ xmid, const float* __restrict__ n2w,
    const float* __restrict__ invr,
    const float* __restrict__ gate_w, const float* __restrict__ gate_b,
    const float* __restrict__ noise_w, const float* __restrict__ noise_b,
    const float* __restrict__ rnoise,
    int* __restrict__ tokE, float* __restrict__ tokS,
    int* __restrict__ cnt, float* __restrict__ imp)
{
  const int t=blockIdx.x, tid=threadIdx.x;
  const float r=invr[t];
  float acc[16];
  #pragma unroll
  for(int e=0;e<16;e++) acc[e]=0.f;
  const float* xr=xmid+(size_t)t*DM;
  #pragma unroll
  for(int i=0;i<4;i++){
    int d=tid*4+i;
    float h=n2w[d]*xr[d]*r;
    const float* gwr=gate_w+(size_t)d*8;
    const float* nwr=noise_w+(size_t)d*8;
    #pragma unroll
    for(int e=0;e<8;e++){ acc[e]+=h*gwr[e]; acc[8+e]+=h*nwr[e]; }
  }
  #pragma unroll
  for(int e=0;e<16;e++){
    #pragma unroll
    for(int o=32;o;o>>=1) acc[e]+=__shfl_down(acc[e],o,64);
  }
  __shared__ float red[4][16];
  if((tid&63)==0){
    #pragma unroll
    for(int e=0;e<16;e++) red[tid>>6][e]=acc[e];
  }
  __syncthreads();
  if(tid==0){
    float lgt[8];
    #pragma unroll
    for(int e=0;e<8;e++){
      float g =red[0][e]+red[1][e]+red[2][e]+red[3][e];
      float nz=red[0][8+e]+red[1][8+e]+red[2][8+e]+red[3][8+e];
      lgt[e]=g+gate_b[e]+nz+noise_b[e]+rnoise[(size_t)t*8+e];
    }
    int i1=0;
    for(int e=1;e<8;e++) if(lgt[e]>lgt[i1]) i1=e;
    int i2=(i1==0)?1:0;
    for(int e=0;e<8;e++) if(e!=i1 && lgt[e]>lgt[i2]) i2=e;
    float e2=expf(lgt[i2]-lgt[i1]);
    float den=1.f+e2;
    float s1=1.f/den, s2=e2/den;
    tokE[2*t]=i1; tokE[2*t+1]=i2;
    tokS[2*t]=s1; tokS[2*t+1]=s2;
    atomicAdd(&cnt[i1],1); atomicAdd(&cnt[i2],1);
    atomicAdd(&imp[i1],s1); atomicAdd(&imp[i2],s2);
  }
}

// ---------------- offsets scan + aux loss ----------------
__global__ void scan_aux(const int* cnt, int* off, int* cur, const float* imp, float* auxout)
{
  if(threadIdx.x==0){
    int o=0;
    for(int e=0;e<8;e++){ off[e]=o; o+=cnt[e]; cur[e]=0; }
    float u=0.125f, s=0.f;
    for(int e=0;e<8;e++) s+=u*(logf(u)-logf(imp[e]*(1.f/4096.f)+1e-8f));
    auxout[0]=s;
  }
}

// ---------------- compact token lists per expert ----------------
__global__ __launch_bounds__(256) void scatter_kernel(const int* __restrict__ tokE,
    const int* __restrict__ off, int* __restrict__ cur,
    int* __restrict__ tokL, int* __restrict__ slotOf)
{
  int t=blockIdx.x*256+threadIdx.x;
  if(t>=TKN) return;
  #pragma unroll
  for(int j=0;j<2;j++){
    int e=tokE[2*t+j];
    int idx=atomicAdd(&cur[e],1);
    int slot=off[e]+idx;
    tokL[slot]=t;
    slotOf[2*t+j]=slot;
  }
}

// ---------------- combine: dout[t] += s1*eo[slot1] + s2*eo[slot2] (eo bf16) ----
__global__ __launch_bounds__(256) void combine_kernel(const short* __restrict__ eo,
    const int* __restrict__ slotOf, const float* __restrict__ tokS,
    float* __restrict__ dout)
{
  const int t=blockIdx.x, d=threadIdx.x*4;
  const int s1=slotOf[2*t], s2=slotOf[2*t+1];
  const float w1=tokS[2*t], w2=tokS[2*t+1];
  float4 o=*(float4*)(dout+(size_t)t*DM+d);
  const short4 e1=*(const short4*)(eo+(size_t)s1*DM+d);
  const short4 e2=*(const short4*)(eo+(size_t)s2*DM+d);
  o.x+=w1*bf2f(e1.x)+w2*bf2f(e2.x);
  o.y+=w1*bf2f(e1.y)+w2*bf2f(e2.y);
  o.z+=w1*bf2f(e1.z)+w2*bf2f(e2.z);
  o.w+=w1*bf2f(e1.w)+w2*bf2f(e2.w);
  *(float4*)(dout+(size_t)t*DM+d)=o;
}

extern "C" void kernel_launch(void* const* d_in, const int* in_sizes, int n_in,
                              void* d_out, int out_size, void* d_ws, size_t ws_size,
                              hipStream_t stream)
{
  const float* x   =(const float*)d_in[0];
  const float* rn  =(const float*)d_in[1];
  const float* n1w =(const float*)d_in[2];
  const float* n2w =(const float*)d_in[3];
  const float* wq  =(const float*)d_in[4];
  const float* wk  =(const float*)d_in[5];
  const float* wv  =(const float*)d_in[6];
  const float* wo  =(const float*)d_in[7];
  const float* gw  =(const float*)d_in[8];
  const float* gb  =(const float*)d_in[9];
  const float* nw  =(const float*)d_in[10];
  const float* nb  =(const float*)d_in[11];
  const float* ew1 =(const float*)d_in[12];
  const float* eb1 =(const float*)d_in[13];
  const float* ew2 =(const float*)d_in[14];
  const float* eb2 =(const float*)d_in[15];
  float* dout=(float*)d_out;

  char* p=(char*)d_ws;
  auto take=[&](size_t n){ char* q=p; p+=(n+255)&~(size_t)255; return q; };
  short* h1    =(short*)take((size_t)TKN*DM*2);
  short* wqkvT =(short*)take((size_t)1536*DM*2);
  short* woT   =(short*)take((size_t)DM*DM*2);
  short* ew1T  =(short*)take((size_t)NE*DFF*DM*2);
  short* ew2T  =(short*)take((size_t)NE*DM*DFF*2);
  short* QKV   =(short*)take((size_t)TKN*1536*2);
  short* VTb   =(short*)take((size_t)8*64*2048*2);
  short* Ob    =(short*)take((size_t)TKN*DM*2);
  float* invr  =(float*)take((size_t)TKN*4);
  short* hh    =(short*)take((size_t)2*TKN*DFF*2);
  short* eoB   =(short*)take((size_t)2*TKN*DM*2);
  int*   tokE  =(int*)take((size_t)TKN*2*4);
  float* tokS  =(float*)take((size_t)TKN*2*4);
  int*   tokL  =(int*)take((size_t)2*TKN*4);
  int*   slotOf=(int*)take((size_t)TKN*2*4);
  int*   cnt   =(int*)take(256);
  int*   off   =cnt+8;
  int*   cur   =cnt+16;
  float* imp   =(float*)(cnt+24);

  initk<<<1,64,0,stream>>>(cnt,imp);
  rms_kernel<0><<<TKN,256,0,stream>>>(x,n1w,h1,nullptr);
  transp_f2b<<<dim3(32,16,1),256,0,stream>>>(wq,wqkvT,DM,DM);
  transp_f2b<<<dim3(8,16,1),256,0,stream>>>(wk,wqkvT+(size_t)1024*DM,DM,256);
  transp_f2b<<<dim3(8,16,1),256,0,stream>>>(wv,wqkvT+(size_t)1280*DM,DM,256);
  transp_f2b<<<dim3(32,16,1),256,0,stream>>>(wo,woT,DM,DM);
  transp_f2b<<<dim3(128,16,8),256,0,stream>>>(ew1,ew1T,DM,DFF);
  transp_f2b<<<dim3(32,64,8),256,0,stream>>>(ew2,ew2T,DFF,DM);

  // QKV projection: [4096][1536]
  gemm128k<0,false,false><<<dim3(12,32),256,0,stream>>>(
      h1,wqkvT,TKN,1536,DM,0, nullptr,nullptr,nullptr,
      QKV,1536,0, nullptr,nullptr, nullptr,0);
  transpV<<<dim3(64,2,8),256,0,stream>>>(QKV,VTb);
  rope_kernel<<<10240,256,0,stream>>>(QKV);
  attn_kernel<<<dim3(16,16,2),256,0,stream>>>(QKV,VTb,Ob);
  // O projection + residual
  gemm128k<1,false,false><<<dim3(8,32),256,0,stream>>>(
      Ob,woT,TKN,DM,DM,0, nullptr,nullptr,nullptr,
      nullptr,DM,0, dout,x, nullptr,0);

  rms_kernel<1><<<TKN,256,0,stream>>>(dout,n2w,h1,invr);
  router_kernel<<<TKN,256,0,stream>>>(dout,n2w,invr,gw,gb,nw,nb,rn,tokE,tokS,cnt,imp);
  scan_aux<<<1,64,0,stream>>>(cnt,off,cur,imp,dout+(size_t)TKN*DM);
  scatter_kernel<<<16,256,0,stream>>>(tokE,off,cur,tokL,slotOf);

  // MoE GEMM1: hh = silu(h2[tokL] @ ew1 + eb1)
  gemm128k<2,true,true><<<dim3(32,32,8),256,0,stream>>>(
      h1,ew1T,0,DFF,DM,DFF*DM, cnt,off,tokL,
      hh,DFF,0, nullptr,nullptr, eb1,DFF);
  // MoE GEMM2: eo = hh @ ew2 + eb2   (bf16 output)
  gemm128k<3,false,true><<<dim3(8,32,8),256,0,stream>>>(
      hh,ew2T,0,DM,DFF,DM*DFF, cnt,off,nullptr,
      eoB,DM,0, nullptr,nullptr, eb2,DM);
  combine_kernel<<<TKN,256,0,stream>>>(eoB,slotOf,tokS,dout);
  (void)in_sizes;(void)n_in;(void)out_size;(void)ws_size;
}

// Round 17
// 671.676 us; speedup vs baseline: 1.0510x; 1.0405x over previous
//
#include <hip/hip_runtime.h>

// DecoderLayer: rms1 -> QKV -> RoPE -> causal GQA attn -> O+resid -> rms2
// -> noisy top-2 router -> sparse MoE -> resid ; aux loss.
// B=2 S=2048 D=1024 NQ=16 NKV=4 HD=64 E=8 DFF=4096 top_k=2
// r16 baseline 698.9 us; r17: kernel fusion (17 -> 13 launches), router fused
// into rms2 (keeps h in regs, drops 16MB re-read + invr buffer).

#define TKN 4096
#define DM  1024
#define DFF 4096
#define NE  8
#define NEG_INF -3.0e38f
#define BM 128
#define BK 64

typedef __attribute__((ext_vector_type(8))) short short8;
typedef __attribute__((ext_vector_type(4))) float f32x4;

#define MFMA16(a,b,c) __builtin_amdgcn_mfma_f32_16x16x32_bf16(a,b,c,0,0,0)

__device__ __forceinline__ short f2bf(float f){
  union{float f;unsigned u;}v; v.f=f;
  unsigned r=v.u+0x7fffu+((v.u>>16)&1u);
  return (short)(r>>16);
}
__device__ __forceinline__ float bf2f(short s){
  union{unsigned u;float f;}v; v.u=((unsigned)(unsigned short)s)<<16; return v.f;
}
__device__ __forceinline__ void gload16(const short* g, short* l){
  __builtin_amdgcn_global_load_lds(
      (const __attribute__((address_space(1))) void*)g,
      (__attribute__((address_space(3))) void*)l, 16, 0, 0);
}

// ---------------- RMSNorm 1 (+ cnt/imp init in block 0), writes bf16 ----------
__global__ __launch_bounds__(256) void rms1_kernel(const float* __restrict__ x,
    const float* __restrict__ w, short* __restrict__ out,
    int* __restrict__ cnt, float* __restrict__ imp)
{
  const int row=blockIdx.x, tid=threadIdx.x;
  if(row==0 && tid<8){ cnt[tid]=0; imp[tid]=0.f; }
  const float4 xv=((const float4*)(x+(size_t)row*DM))[tid];
  float s=xv.x*xv.x+xv.y*xv.y+xv.z*xv.z+xv.w*xv.w;
  #pragma unroll
  for(int o=32;o;o>>=1) s+=__shfl_down(s,o,64);
  __shared__ float red[4];
  if((tid&63)==0) red[tid>>6]=s;
  __syncthreads();
  float r=rsqrtf((red[0]+red[1]+red[2]+red[3])*(1.f/DM)+1e-8f);
  const float4 wv=((const float4*)w)[tid];
  short* op=out+(size_t)row*DM+tid*4;
  op[0]=f2bf(wv.x*xv.x*r); op[1]=f2bf(wv.y*xv.y*r);
  op[2]=f2bf(wv.z*xv.z*r); op[3]=f2bf(wv.w*xv.w*r);
}

// ---------------- fused attention-weight transposes (wq,wk,wv,wo) -------------
// grid (32,16,4); z selects src/dst; 64x32 tiles, float4 reads, short4 writes.
__global__ __launch_bounds__(256) void transpW4(
    const float* __restrict__ wq, const float* __restrict__ wk,
    const float* __restrict__ wv, const float* __restrict__ wo,
    short* __restrict__ wqkvT, short* __restrict__ woT)
{
  const float* in; short* out; int C;
  switch(blockIdx.z){
    case 0:  in=wq; out=wqkvT;                      C=1024; break;
    case 1:  in=wk; out=wqkvT+(size_t)1024*DM;      C=256;  break;
    case 2:  in=wv; out=wqkvT+(size_t)1280*DM;      C=256;  break;
    default: in=wo; out=woT;                        C=1024; break;
  }
  const int R=1024;
  const int r0=blockIdx.y*64, c0=blockIdx.x*32;
  if(c0>=C) return;
  __shared__ float t[64][33];
  const int tid=threadIdx.x;
  #pragma unroll
  for(int p=0;p<2;p++){
    int slot=p*256+tid;
    int ry=slot>>3, rx=slot&7;
    float4 v=*(const float4*)(in+(size_t)(r0+ry)*C+c0+rx*4);
    t[ry][rx*4+0]=v.x; t[ry][rx*4+1]=v.y; t[ry][rx*4+2]=v.z; t[ry][rx*4+3]=v.w;
  }
  __syncthreads();
  #pragma unroll
  for(int p=0;p<2;p++){
    int slot=p*256+tid;
    int cy=slot>>4, cx=slot&15;
    short4 o4;
    o4.x=f2bf(t[cx*4+0][cy]); o4.y=f2bf(t[cx*4+1][cy]);
    o4.z=f2bf(t[cx*4+2][cy]); o4.w=f2bf(t[cx*4+3][cy]);
    *(short4*)(out+(size_t)(c0+cy)*R+r0+cx*4)=o4;
  }
}

// ---------------- fused expert-weight transposes (ew1,ew2) -------------------
// grid (128,32,8): y<16 -> ew1 tile (x,y) [R=1024,C=4096];
// y>=16 -> idx=x+128*(y-16) in [0,2048): ew2 tile (idx&31, idx>>5) [R=4096,C=1024].
__global__ __launch_bounds__(256) void transpEW(
    const float* __restrict__ ew1, const float* __restrict__ ew2,
    short* __restrict__ ew1T, short* __restrict__ ew2T)
{
  const int e=blockIdx.z;
  const float* in; short* out; int R,C,bx,by;
  if(blockIdx.y<16){
    in=ew1+(size_t)e*DM*DFF; out=ew1T+(size_t)e*DFF*DM;
    R=DM; C=DFF; bx=blockIdx.x; by=blockIdx.y;
  }else{
    int idx=blockIdx.x+128*(blockIdx.y-16);
    in=ew2+(size_t)e*DFF*DM; out=ew2T+(size_t)e*DM*DFF;
    R=DFF; C=DM; bx=idx&31; by=idx>>5;
  }
  const int r0=by*64, c0=bx*32;
  __shared__ float t[64][33];
  const int tid=threadIdx.x;
  #pragma unroll
  for(int p=0;p<2;p++){
    int slot=p*256+tid;
    int ry=slot>>3, rx=slot&7;
    float4 v=*(const float4*)(in+(size_t)(r0+ry)*C+c0+rx*4);
    t[ry][rx*4+0]=v.x; t[ry][rx*4+1]=v.y; t[ry][rx*4+2]=v.z; t[ry][rx*4+3]=v.w;
  }
  __syncthreads();
  #pragma unroll
  for(int p=0;p<2;p++){
    int slot=p*256+tid;
    int cy=slot>>4, cx=slot&15;
    short4 o4;
    o4.x=f2bf(t[cx*4+0][cy]); o4.y=f2bf(t[cx*4+1][cy]);
    o4.z=f2bf(t[cx*4+2][cy]); o4.w=f2bf(t[cx*4+3][cy]);
    *(short4*)(out+(size_t)(c0+cy)*R+r0+cx*4)=o4;
  }
}

// ---------------- 128x128 tile GEMM, BK=64, swizzled LDS, single-buffer ----
// (r6 config: measured best — 2-barrier, 32KB LDS, conflicts=0)
// LDS chunk (row,col8) holds logical k-chunk col8 ^ (row&7)  (both tiles)
// EPI 0: bf16 store (ldo,ocol)        EPI 1: outf = resid + acc (fp32)
// EPI 2: silu(acc+bias) bf16, MoE row O+r   EPI 3: (acc+bias) bf16, MoE row O+r
template<int EPI, bool GATHER, bool MOE>
__global__ __launch_bounds__(256) void gemm128k(
    const short* __restrict__ Ab, const short* __restrict__ BTb,
    int Mfix, int N, int K, int ldb_e,
    const int* __restrict__ cnt, const int* __restrict__ off,
    const int* __restrict__ tokL,
    short* __restrict__ outb, int ldo, int ocol,
    float* __restrict__ outf, const float* __restrict__ resid,
    const float* __restrict__ biasb, int ldbias)
{
  __shared__ short As[BM*BK];
  __shared__ short Bs[BM*BK];
  const int e  = MOE ? blockIdx.z : 0;
  const int M  = MOE ? cnt[e] : Mfix;
  const int tm = blockIdx.y;
  if (tm*BM >= M) return;
  const int tn = blockIdx.x;
  const int O  = MOE ? off[e] : 0;
  const short* BT = BTb + (size_t)e * (size_t)ldb_e;

  const int tid = threadIdx.x;
  const int w = tid>>6, lane = tid&63;
  const int lr = lane&15, lg = lane>>4;
  const int wr = (w>>1)*64, wc = (w&1)*64;

  const short* pA[4]; const short* pB[4];
  #pragma unroll
  for(int i=0;i<4;i++){
    int c = i*256 + w*64 + lane;
    int cs = c ^ ((c>>3)&7);
    int r = cs>>3, k8 = (cs&7)*8;
    int grA = tm*BM + r; if (grA > M-1) grA = M-1;
    if (GATHER)      pA[i] = Ab + (size_t)tokL[O+grA]*K + k8;
    else if (MOE)    pA[i] = Ab + (size_t)(O+grA)*K + k8;
    else             pA[i] = Ab + (size_t)grA*K + k8;
    pB[i] = BT + (size_t)(tn*BM + r)*K + k8;
  }
  short* lA[4]; short* lB[4];
  #pragma unroll
  for(int i=0;i<4;i++){ lA[i]=As+i*2048+w*512; lB[i]=Bs+i*2048+w*512; }

  f32x4 acc[4][4];
  #pragma unroll
  for(int i=0;i<4;i++)
    #pragma unroll
    for(int j=0;j<4;j++) acc[i][j]=(f32x4){0.f,0.f,0.f,0.f};

  #pragma unroll
  for(int i=0;i<4;i++){ gload16(pA[i], lA[i]); gload16(pB[i], lB[i]); }

  const int koff0 = ((lg  ) ^ (lr&7))*8;
  const int koff1 = ((4+lg) ^ (lr&7))*8;

  for(int k0=0;k0<K;k0+=BK){
    __syncthreads();
    short8 af[4][2], bfr[4][2];
    #pragma unroll
    for(int mi=0;mi<4;mi++){
      const int rb=(wr+mi*16+lr)*BK;
      af[mi][0]=*(const short8*)(As+rb+koff0);
      af[mi][1]=*(const short8*)(As+rb+koff1);
    }
    #pragma unroll
    for(int ni=0;ni<4;ni++){
      const int rb=(wc+ni*16+lr)*BK;
      bfr[ni][0]=*(const short8*)(Bs+rb+koff0);
      bfr[ni][1]=*(const short8*)(Bs+rb+koff1);
    }
    __syncthreads();
    if(k0+BK<K){
      #pragma unroll
      for(int i=0;i<4;i++){ gload16(pA[i]+k0+BK, lA[i]); gload16(pB[i]+k0+BK, lB[i]); }
    }
    #pragma unroll
    for(int kk=0;kk<2;kk++)
      #pragma unroll
      for(int mi=0;mi<4;mi++)
        #pragma unroll
        for(int ni=0;ni<4;ni++)
          acc[mi][ni]=MFMA16(af[mi][kk],bfr[ni][kk],acc[mi][ni]);
  }

  #pragma unroll
  for(int mi=0;mi<4;mi++){
    const int rb = tm*BM + wr + mi*16 + 4*lg;
    #pragma unroll
    for(int ni=0;ni<4;ni++){
      const int col = tn*BM + wc + ni*16 + lr;
      f32x4 a = acc[mi][ni];
      #pragma unroll
      for(int j=0;j<4;j++){
        int r = rb + j;
        if (r < M){
          if (EPI==0){
            outb[(size_t)r*ldo + ocol + col] = f2bf(a[j]);
          } else if (EPI==1){
            size_t idx=(size_t)r*ldo + col;
            outf[idx] = resid[idx] + a[j];
          } else if (EPI==2){
            float v=a[j]+biasb[(size_t)e*ldbias+col];
            v=v/(1.f+__expf(-v));
            outb[(size_t)(O+r)*ldo + col]=f2bf(v);
          } else {
            outb[(size_t)(O+r)*ldo + col]=f2bf(a[j]+biasb[(size_t)e*ldbias+col]);
          }
        }
      }
    }
  }
}

// ---------------- fused RoPE + V-transpose ----------------
// grid 11264 blocks x 256. id<1024: V-transpose tile (x=id&63, y=(id>>6)&1,
// z=id>>7). id>=1024: RoPE thread t=(id-1024)*256+tid (same coverage as before).
__global__ __launch_bounds__(256) void ropeV_kernel(short* __restrict__ QKV,
    short* __restrict__ VT)
{
  const int id=blockIdx.x;
  const int tid=threadIdx.x;
  __shared__ short tls[32][33];
  if(id<1024){
    const int z=id>>7, b=z>>2, kvh=z&3;
    const int s0=(id&63)*32, d0=((id>>6)&1)*32;
    const int tx=tid&31, ty=tid>>5;
    #pragma unroll
    for(int i=0;i<4;i++)
      tls[ty+i*8][tx]=QKV[(size_t)(b*2048+s0+ty+i*8)*1536+1280+kvh*64+d0+tx];
    __syncthreads();
    #pragma unroll
    for(int i=0;i<4;i++)
      VT[((size_t)(b*4+kvh)*64+d0+ty+i*8)*2048+s0+tx]=tls[tx][ty+i*8];
    return;
  }
  int t=(id-1024)*256+tid;
  if(t>=2621440) return;
  size_t addr; int s,i;
  if(t<2097152){                  // Q
    i=t&31; int rh=t>>5; int bs=rh>>4, h=rh&15; s=bs&2047;
    addr=(size_t)bs*1536+h*64+2*i;
  }else{                          // K
    t-=2097152;
    i=t&31; int rh=t>>5; int bs=rh>>2, h=rh&3; s=bs&2047;
    addr=(size_t)bs*1536+1024+h*64+2*i;
  }
  float inv=__expf(-(float)i*0.28782313662425572f); // ln(10000)/32
  float ang=(float)s*inv;
  float c=__cosf(ang), sn=__sinf(ang);
  float xe=bf2f(QKV[addr]), xo=bf2f(QKV[addr+1]);
  QKV[addr]  =f2bf(xe*c-xo*sn);
  QKV[addr+1]=f2bf(xo*c+xe*sn);
}

// ---------------- causal GQA flash attention v3 (load-balanced) ----------------
// grid (16, NQ, B); qt = (b==0) ? x : 15-x. 4 waves; wave owns 32 q rows;
// KVBLK=64. K tile [64][64] and VT tile [64][64] staged via global_load_lds,
// both-sides XOR swizzle (8-elem chunks XOR'd by row&7).
__global__ __launch_bounds__(256) void attn_kernel(
    const short* __restrict__ QKV, const short* __restrict__ VT,
    short* __restrict__ O)
{
  const int b=blockIdx.z;
  const int qt = b==0 ? (int)blockIdx.x : 15-(int)blockIdx.x;
  const int h=blockIdx.y;
  const int kvh=h>>2;
  const int tid=threadIdx.x;
  const int w=tid>>6, lane=tid&63;
  const int lr=lane&15, lg=lane>>4;
  const int q0w=qt*128+w*32;

  __shared__ short Ks[64*64];
  __shared__ short Vs[64*64];
  __shared__ short Ps[4][32][72];

  short8 qf[2][2];
  #pragma unroll
  for(int qb=0;qb<2;qb++)
    #pragma unroll
    for(int ks=0;ks<2;ks++)
      qf[qb][ks]=*(const short8*)(QKV+(size_t)(b*2048+q0w+qb*16+lr)*1536+h*64+ks*32+lg*8);

  f32x4 o[2][4];
  float mj[2][4], lj[2][4];
  #pragma unroll
  for(int qb=0;qb<2;qb++)
    #pragma unroll
    for(int j=0;j<4;j++){
      mj[qb][j]=NEG_INF; lj[qb][j]=0.f;
      #pragma unroll
      for(int db=0;db<4;db++) o[qb][db]=(f32x4){0.f,0.f,0.f,0.f};
    }

  const int c1=w*64+lane;
  const int r1=c1>>3, swz=((c1&7)^(r1&7))*8;
  const short* gKb = QKV + 1024 + kvh*64 + (size_t)r1*1536 + swz;
  const short* gVb = VT + ((size_t)(b*4+kvh)*64 + r1)*2048 + swz;
  short* lK1=Ks+w*512; short* lK2=Ks+2048+w*512;
  short* lV1=Vs+w*512; short* lV2=Vs+2048+w*512;

  auto stage=[&](int kv0){
    const short* gK = gKb + (size_t)(b*2048+kv0)*1536;
    gload16(gK, lK1);
    gload16(gK + (size_t)32*1536, lK2);
    const short* gV = gVb + kv0;
    gload16(gV, lV1);
    gload16(gV + (size_t)32*2048, lV2);
  };

  const int kvend=qt*128+127;
  stage(0);
  for(int kv0=0;kv0<=kvend;kv0+=64){
    __syncthreads();
    const bool act = (kv0 <= q0w+31);
    short8 kf[4][2], vf[4][2];
    if(act){
      #pragma unroll
      for(int nb=0;nb<4;nb++)
        #pragma unroll
        for(int ks=0;ks<2;ks++)
          kf[nb][ks]=*(const short8*)(Ks+(nb*16+lr)*64+(((ks*4+lg)^(lr&7))*8));
      #pragma unroll
      for(int db=0;db<4;db++)
        #pragma unroll
        for(int ks=0;ks<2;ks++)
          vf[db][ks]=*(const short8*)(Vs+(db*16+lr)*64+(((ks*4+lg)^(lr&7))*8));
    }
    __syncthreads();
    if(kv0+64<=kvend) stage(kv0+64);
    if(!act) continue;

    f32x4 s[2][4];
    #pragma unroll
    for(int qb=0;qb<2;qb++)
      #pragma unroll
      for(int nb=0;nb<4;nb++){
        f32x4 t=(f32x4){0.f,0.f,0.f,0.f};
        t=MFMA16(qf[qb][0],kf[nb][0],t);
        t=MFMA16(qf[qb][1],kf[nb][1],t);
        s[qb][nb]=t;
      }

    const bool edge = (kv0+63 > q0w);
    float tmx[2][4];
    #pragma unroll
    for(int qb=0;qb<2;qb++)
      #pragma unroll
      for(int j=0;j<4;j++){
        float mx=NEG_INF;
        #pragma unroll
        for(int nb=0;nb<4;nb++){
          float v=s[qb][nb][j]*0.125f;
          if(edge){
            if(kv0+nb*16+lr > q0w+qb*16+4*lg+j) v=NEG_INF;
          }
          s[qb][nb][j]=v;
          mx=fmaxf(mx,v);
        }
        tmx[qb][j]=mx;
      }
    #pragma unroll
    for(int qb=0;qb<2;qb++)
      #pragma unroll
      for(int j=0;j<4;j++){
        #pragma unroll
        for(int od=1;od<16;od<<=1) tmx[qb][j]=fmaxf(tmx[qb][j],__shfl_xor(tmx[qb][j],od,64));
      }
    #pragma unroll
    for(int qb=0;qb<2;qb++)
      #pragma unroll
      for(int j=0;j<4;j++){
        float mn=fmaxf(mj[qb][j],tmx[qb][j]);
        float al=__expf(mj[qb][j]-mn);
        mj[qb][j]=mn;
        float rs=0.f;
        #pragma unroll
        for(int nb=0;nb<4;nb++){
          float pv=__expf(s[qb][nb][j]-mn);
          s[qb][nb][j]=pv;
          rs+=pv;
        }
        #pragma unroll
        for(int od=1;od<16;od<<=1) rs+=__shfl_xor(rs,od,64);
        lj[qb][j]=lj[qb][j]*al+rs;
        #pragma unroll
        for(int db=0;db<4;db++) o[qb][db][j]*=al;
      }
    #pragma unroll
    for(int qb=0;qb<2;qb++)
      #pragma unroll
      for(int nb=0;nb<4;nb++)
        #pragma unroll
        for(int j=0;j<4;j++)
          Ps[w][qb*16+4*lg+j][nb*16+lr]=f2bf(s[qb][nb][j]);
    short8 pa[2][2];
    #pragma unroll
    for(int qb=0;qb<2;qb++)
      #pragma unroll
      for(int ks=0;ks<2;ks++)
        pa[qb][ks]=*(const short8*)(&Ps[w][qb*16+lr][ks*32+lg*8]);
    #pragma unroll
    for(int qb=0;qb<2;qb++)
      #pragma unroll
      for(int db=0;db<4;db++){
        o[qb][db]=MFMA16(pa[qb][0],vf[db][0],o[qb][db]);
        o[qb][db]=MFMA16(pa[qb][1],vf[db][1],o[qb][db]);
      }
  }

  #pragma unroll
  for(int qb=0;qb<2;qb++)
    #pragma unroll
    for(int j=0;j<4;j++){
      const int qpos=q0w+qb*16+4*lg+j;
      const float inv=1.f/lj[qb][j];
      size_t base=(size_t)(b*2048+qpos)*DM+h*64;
      #pragma unroll
      for(int db=0;db<4;db++)
        O[base+db*16+lr]=f2bf(o[qb][db][j]*inv);
    }
}

// ---------------- fused RMSNorm-2 + router ----------------
// Computes r + h2 (fp32 in regs), writes h2 bf16, then router logits/top-2
// directly from the register h2 (identical math to the previous two kernels).
__global__ __launch_bounds__(256) void rms2_router(
    const float* __restrict__ xmid, const float* __restrict__ n2w,
    const float* __restrict__ gate_w, const float* __restrict__ gate_b,
    const float* __restrict__ noise_w, const float* __restrict__ noise_b,
    const float* __restrict__ rnoise,
    short* __restrict__ h2out,
    int* __restrict__ tokE, float* __restrict__ tokS,
    int* __restrict__ cnt, float* __restrict__ imp)
{
  const int t=blockIdx.x, tid=threadIdx.x;
  const float4 xv=((const float4*)(xmid+(size_t)t*DM))[tid];
  float s=xv.x*xv.x+xv.y*xv.y+xv.z*xv.z+xv.w*xv.w;
  #pragma unroll
  for(int o=32;o;o>>=1) s+=__shfl_down(s,o,64);
  __shared__ float red[4];
  if((tid&63)==0) red[tid>>6]=s;
  __syncthreads();
  const float r=rsqrtf((red[0]+red[1]+red[2]+red[3])*(1.f/DM)+1e-8f);
  const float4 wv=((const float4*)n2w)[tid];
  float hreg[4]={wv.x*xv.x*r, wv.y*xv.y*r, wv.z*xv.z*r, wv.w*xv.w*r};
  short* op=h2out+(size_t)t*DM+tid*4;
  op[0]=f2bf(hreg[0]); op[1]=f2bf(hreg[1]);
  op[2]=f2bf(hreg[2]); op[3]=f2bf(hreg[3]);

  float acc[16];
  #pragma unroll
  for(int e=0;e<16;e++) acc[e]=0.f;
  #pragma unroll
  for(int i=0;i<4;i++){
    int d=tid*4+i;
    const float* gwr=gate_w+(size_t)d*8;
    const float* nwr=noise_w+(size_t)d*8;
    #pragma unroll
    for(int e=0;e<8;e++){ acc[e]+=hreg[i]*gwr[e]; acc[8+e]+=hreg[i]*nwr[e]; }
  }
  #pragma unroll
  for(int e=0;e<16;e++){
    #pragma unroll
    for(int o=32;o;o>>=1) acc[e]+=__shfl_down(acc[e],o,64);
  }
  __shared__ float red2[4][16];
  if((tid&63)==0){
    #pragma unroll
    for(int e=0;e<16;e++) red2[tid>>6][e]=acc[e];
  }
  __syncthreads();
  if(tid==0){
    float lgt[8];
    #pragma unroll
    for(int e=0;e<8;e++){
      float g =red2[0][e]+red2[1][e]+red2[2][e]+red2[3][e];
      float nz=red2[0][8+e]+red2[1][8+e]+red2[2][8+e]+red2[3][8+e];
      lgt[e]=g+gate_b[e]+nz+noise_b[e]+rnoise[(size_t)t*8+e];
    }
    int i1=0;
    for(int e=1;e<8;e++) if(lgt[e]>lgt[i1]) i1=e;
    int i2=(i1==0)?1:0;
    for(int e=0;e<8;e++) if(e!=i1 && lgt[e]>lgt[i2]) i2=e;
    float e2=expf(lgt[i2]-lgt[i1]);
    float den=1.f+e2;
    float s1=1.f/den, s2=e2/den;
    tokE[2*t]=i1; tokE[2*t+1]=i2;
    tokS[2*t]=s1; tokS[2*t+1]=s2;
    atomicAdd(&cnt[i1],1); atomicAdd(&cnt[i2],1);
    atomicAdd(&imp[i1],s1); atomicAdd(&imp[i2],s2);
  }
}

// ---------------- offsets scan + aux loss ----------------
__global__ void scan_aux(const int* cnt, int* off, int* cur, const float* imp, float* auxout)
{
  if(threadIdx.x==0){
    int o=0;
    for(int e=0;e<8;e++){ off[e]=o; o+=cnt[e]; cur[e]=0; }
    float u=0.125f, s=0.f;
    for(int e=0;e<8;e++) s+=u*(logf(u)-logf(imp[e]*(1.f/4096.f)+1e-8f));
    auxout[0]=s;
  }
}

// ---------------- compact token lists per expert ----------------
__global__ __launch_bounds__(256) void scatter_kernel(const int* __restrict__ tokE,
    const int* __restrict__ off, int* __restrict__ cur,
    int* __restrict__ tokL, int* __restrict__ slotOf)
{
  int t=blockIdx.x*256+threadIdx.x;
  if(t>=TKN) return;
  #pragma unroll
  for(int j=0;j<2;j++){
    int e=tokE[2*t+j];
    int idx=atomicAdd(&cur[e],1);
    int slot=off[e]+idx;
    tokL[slot]=t;
    slotOf[2*t+j]=slot;
  }
}

// ---------------- combine: dout[t] += s1*eo[slot1] + s2*eo[slot2] (eo bf16) ----
__global__ __launch_bounds__(256) void combine_kernel(const short* __restrict__ eo,
    const int* __restrict__ slotOf, const float* __restrict__ tokS,
    float* __restrict__ dout)
{
  const int t=blockIdx.x, d=threadIdx.x*4;
  const int s1=slotOf[2*t], s2=slotOf[2*t+1];
  const float w1=tokS[2*t], w2=tokS[2*t+1];
  float4 o=*(float4*)(dout+(size_t)t*DM+d);
  const short4 e1=*(const short4*)(eo+(size_t)s1*DM+d);
  const short4 e2=*(const short4*)(eo+(size_t)s2*DM+d);
  o.x+=w1*bf2f(e1.x)+w2*bf2f(e2.x);
  o.y+=w1*bf2f(e1.y)+w2*bf2f(e2.y);
  o.z+=w1*bf2f(e1.z)+w2*bf2f(e2.z);
  o.w+=w1*bf2f(e1.w)+w2*bf2f(e2.w);
  *(float4*)(dout+(size_t)t*DM+d)=o;
}

extern "C" void kernel_launch(void* const* d_in, const int* in_sizes, int n_in,
                              void* d_out, int out_size, void* d_ws, size_t ws_size,
                              hipStream_t stream)
{
  const float* x   =(const float*)d_in[0];
  const float* rn  =(const float*)d_in[1];
  const float* n1w =(const float*)d_in[2];
  const float* n2w =(const float*)d_in[3];
  const float* wq  =(const float*)d_in[4];
  const float* wk  =(const float*)d_in[5];
  const float* wv  =(const float*)d_in[6];
  const float* wo  =(const float*)d_in[7];
  const float* gw  =(const float*)d_in[8];
  const float* gb  =(const float*)d_in[9];
  const float* nw  =(const float*)d_in[10];
  const float* nb  =(const float*)d_in[11];
  const float* ew1 =(const float*)d_in[12];
  const float* eb1 =(const float*)d_in[13];
  const float* ew2 =(const float*)d_in[14];
  const float* eb2 =(const float*)d_in[15];
  float* dout=(float*)d_out;

  char* p=(char*)d_ws;
  auto take=[&](size_t n){ char* q=p; p+=(n+255)&~(size_t)255; return q; };
  short* h1    =(short*)take((size_t)TKN*DM*2);
  short* wqkvT =(short*)take((size_t)1536*DM*2);
  short* woT   =(short*)take((size_t)DM*DM*2);
  short* ew1T  =(short*)take((size_t)NE*DFF*DM*2);
  short* ew2T  =(short*)take((size_t)NE*DM*DFF*2);
  short* QKV   =(short*)take((size_t)TKN*1536*2);
  short* VTb   =(short*)take((size_t)8*64*2048*2);
  short* Ob    =(short*)take((size_t)TKN*DM*2);
  short* hh    =(short*)take((size_t)2*TKN*DFF*2);
  short* eoB   =(short*)take((size_t)2*TKN*DM*2);
  int*   tokE  =(int*)take((size_t)TKN*2*4);
  float* tokS  =(float*)take((size_t)TKN*2*4);
  int*   tokL  =(int*)take((size_t)2*TKN*4);
  int*   slotOf=(int*)take((size_t)TKN*2*4);
  int*   cnt   =(int*)take(256);
  int*   off   =cnt+8;
  int*   cur   =cnt+16;
  float* imp   =(float*)(cnt+24);

  // rms1 (+ cnt/imp zero in block 0)
  rms1_kernel<<<TKN,256,0,stream>>>(x,n1w,h1,cnt,imp);
  // fused weight transposes
  transpW4<<<dim3(32,16,4),256,0,stream>>>(wq,wk,wv,wo,wqkvT,woT);
  transpEW<<<dim3(128,32,8),256,0,stream>>>(ew1,ew2,ew1T,ew2T);

  // QKV projection: [4096][1536]
  gemm128k<0,false,false><<<dim3(12,32),256,0,stream>>>(
      h1,wqkvT,TKN,1536,DM,0, nullptr,nullptr,nullptr,
      QKV,1536,0, nullptr,nullptr, nullptr,0);
  // fused V-transpose + RoPE
  ropeV_kernel<<<11264,256,0,stream>>>(QKV,VTb);
  attn_kernel<<<dim3(16,16,2),256,0,stream>>>(QKV,VTb,Ob);
  // O projection + residual
  gemm128k<1,false,false><<<dim3(8,32),256,0,stream>>>(
      Ob,woT,TKN,DM,DM,0, nullptr,nullptr,nullptr,
      nullptr,DM,0, dout,x, nullptr,0);

  // fused rms2 + router (h1 reused as h2 buffer)
  rms2_router<<<TKN,256,0,stream>>>(dout,n2w,gw,gb,nw,nb,rn,h1,tokE,tokS,cnt,imp);
  scan_aux<<<1,64,0,stream>>>(cnt,off,cur,imp,dout+(size_t)TKN*DM);
  scatter_kernel<<<16,256,0,stream>>>(tokE,off,cur,tokL,slotOf);

  // MoE GEMM1: hh = silu(h2[tokL] @ ew1 + eb1)
  gemm128k<2,true,true><<<dim3(32,32,8),256,0,stream>>>(
      h1,ew1T,0,DFF,DM,DFF*DM, cnt,off,tokL,
      hh,DFF,0, nullptr,nullptr, eb1,DFF);
  // MoE GEMM2: eo = hh @ ew2 + eb2   (bf16 output)
  gemm128k<3,false,true><<<dim3(8,32,8),256,0,stream>>>(
      hh,ew2T,0,DM,DFF,DM*DFF, cnt,off,nullptr,
      eoB,DM,0, nullptr,nullptr, eb2,DM);
  combine_kernel<<<TKN,256,0,stream>>>(eoB,slotOf,tokS,dout);
  (void)in_sizes;(void)n_in;(void)out_size;(void)ws_size;
}